// Round 1
// 323.959 us; speedup vs baseline: 1.1070x; 1.1070x over previous
//
#include <hip/hip_runtime.h>

constexpr int NL    = 48;
constexpr int SEQ   = 1024;
constexpr int BATCH = 512;

typedef float f2 __attribute__((ext_vector_type(2)));
typedef float f4 __attribute__((ext_vector_type(4)));

__device__ __forceinline__ f2 fma2(f2 a, f2 b, f2 c) {
    return __builtin_elementwise_fma(a, b, c);   // -> v_pk_fma_f32
}

// One step of the linear-domain forward recurrence (LDS-broadcast).
// v (per-lane, lane j owns state j) was written to svl[] at the end of the
// previous step.  This step:
//   1. reads emission ee from the 8-deep ring, prefetches t+8 (1 VMEM)
//   2. mask bit comes from a wave-uniform SGPR ballot (no per-step load)
//   3. (RN_) wave-max of v via 6-op shfl butterfly -> rm_, S  (replaces the
//      47-op serial s_max chain; overlaps the DS round trip)
//   4. broadcasts v via 12 uniform-address ds_read_b128 (conflict-free
//      broadcast reads) -- replaces 48 v_readlane VALU->SGPR ops
//   5. 24 v_pk_fma_f32 against resident Ec2[] column pairs (was 48 v_fmac)
//   6. v = (mt ? acc*ee : v) * rm_;  svl[tid] = v  (1 ds_write, 2 lanes/bank)
// Renorm semantics identical to the readlane version: rm_ = rcp(max(v_pre)),
// scale folded into both mask paths, S += log(max).
#define CRF_STEP(T_, SLOT_, RN_) do {                                         \
    float ee_ = __expf(embuf[SLOT_]);                                         \
    int   mt_ = (int)((mb_cur >> (SLOT_)) & 1);                               \
    int   tn_ = (T_) + 8; if (tn_ > SEQ - 1) tn_ = SEQ - 1;                   \
    embuf[SLOT_] = em[tn_ * NL + jc];                                         \
    float rm_ = 1.0f;                                                         \
    if (RN_) {                                                                \
        float m_ = v;                                                         \
        _Pragma("unroll")                                                     \
        for (int o_ = 32; o_; o_ >>= 1) m_ = fmaxf(m_, __shfl_xor(m_, o_));   \
        rm_ = __builtin_amdgcn_rcpf(m_);                                      \
        S += __logf(m_);                                                      \
    }                                                                         \
    f2 c0_ = {0.f, 0.f}, c1_ = {0.f, 0.f};                                    \
    f2 c2_ = {0.f, 0.f}, c3_ = {0.f, 0.f};                                    \
    _Pragma("unroll")                                                         \
    for (int g_ = 0; g_ < 12; g_ += 2) {                                      \
        f4 s_ = svl4[g_];                                                     \
        c0_ = fma2(s_.xy, Ec2[2 * g_    ], c0_);                              \
        c1_ = fma2(s_.zw, Ec2[2 * g_ + 1], c1_);                              \
        f4 t_ = svl4[g_ + 1];                                                 \
        c2_ = fma2(t_.xy, Ec2[2 * g_ + 2], c2_);                              \
        c3_ = fma2(t_.zw, Ec2[2 * g_ + 3], c3_);                              \
    }                                                                         \
    f2 cs_ = (c0_ + c2_) + (c1_ + c3_);                                       \
    float acc_ = cs_.x + cs_.y;                                               \
    v = (mt_ ? acc_ * ee_ : v) * rm_;                                         \
    svl[tid] = v;                                                             \
} while (0)

// Block = 128: wave 0 = forward recurrence, wave 1 = gold score.
// amdgpu_waves_per_eu(1,1): 512 blocks x 2 waves = 1 wave/SIMD; each forward
// wave owns a SIMD, so step latency is everything.
__global__ __launch_bounds__(128)
__attribute__((amdgpu_waves_per_eu(1, 1)))
void crf_fused(
    const float* __restrict__ emissions, const int* __restrict__ labels,
    const int* __restrict__ mask, const float* __restrict__ trans,
    const float* __restrict__ startt, const float* __restrict__ endt,
    float* __restrict__ gold_out, float* __restrict__ fwd_out)
{
    const int b   = blockIdx.x;
    const int tid = threadIdx.x;
    const float* em = emissions + (size_t)b * SEQ * NL;
    const int*   mk = mask + b * SEQ;

    // broadcast buffer for wave 0 only (wave 1 never touches LDS; no barriers)
    __shared__ alignas(16) float svl[64];

    if (tid < 64) {
        // ---------------- wave 0: forward algorithm ----------------
        const int  j   = tid;                  // lanes 48..63 idle mirrors
        const bool act = (j < NL);
        const int  jc  = act ? j : NL - 1;
        const f4*  svl4 = reinterpret_cast<const f4*>(svl);

        // E column jc as register pairs: Ec2[k] = {exp(T[2k][jc]), exp(T[2k+1][jc])}
        f2 Ec2[24];
        #pragma unroll
        for (int k = 0; k < 24; ++k) {
            f2 e_;
            e_.x = __expf(trans[(2 * k    ) * NL + jc]);
            e_.y = __expf(trans[(2 * k + 1) * NL + jc]);
            Ec2[k] = e_;
        }

        // mask ballots: one vector load + __ballot per 8-step block.
        // bit k of mb_cur = mask[t0 + k] (lanes 8..63 replicate lanes 0..7).
        int mval = mk[tid & 7];                          // steps 0..7 (bit 0 unused)
        unsigned long long mb_cur = __ballot(mval != 0);
        mval = mk[8 + (tid & 7)];                        // preload steps 8..15

        // init: score0 = start + emit[0]; normalize by wave max.
        float s0 = act ? (startt[jc] + em[jc]) : -3.0e38f;
        float m0 = s0;
        #pragma unroll
        for (int o = 32; o; o >>= 1) m0 = fmaxf(m0, __shfl_xor(m0, o));
        float v = act ? __expf(s0 - m0) : 0.0f;
        float S = m0;
        svl[tid] = v;                                    // seed the broadcast buffer

        // 8-deep emission prefetch ring.
        float embuf[8];
        #pragma unroll
        for (int t = 1; t <= 8; ++t) embuf[t & 7] = em[t * NL + jc];

        // peeled steps 1..7; renorm at step 5 (v from step 4).
        CRF_STEP(1, 1, 0); CRF_STEP(2, 2, 0); CRF_STEP(3, 3, 0); CRF_STEP(4, 4, 0);
        CRF_STEP(5, 5, 1); CRF_STEP(6, 6, 0); CRF_STEP(7, 7, 0);

        // aligned chunks of 8: tb = 8,16,...,1016 covers t = 8..1023.
        // renorm at tb+0 and tb+4 -> every <=4 steps (fp32-safe growth).
        for (int tb = 8; tb <= SEQ - 8; tb += 8) {
            mb_cur = __ballot(mval != 0);                // mask bits for tb..tb+7
            int tm = tb + 8 + (tid & 7);                 // prefetch next block's mask
            if (tm > SEQ - 1) tm = SEQ - 1;
            mval = mk[tm];
            CRF_STEP(tb + 0, 0, 1);
            CRF_STEP(tb + 1, 1, 0); CRF_STEP(tb + 2, 2, 0); CRF_STEP(tb + 3, 3, 0);
            CRF_STEP(tb + 4, 4, 1);
            CRF_STEP(tb + 5, 5, 0); CRF_STEP(tb + 6, 6, 0); CRF_STEP(tb + 7, 7, 0);
        }

        // fwd = S + log(sum_j v[j] * exp(end[j])) over active lanes.
        float w = act ? v * __expf(endt[jc]) : 0.0f;
        #pragma unroll
        for (int o = 32; o; o >>= 1) w += __shfl_xor(w, o);
        if (j == 0) fwd_out[b] = S + __logf(w);
    } else {
        // ---------------- wave 1: gold score ----------------
        const int l = tid - 64;
        const int* lb = labels + b * SEQ;

        float part = 0.0f; int mcnt = 0;
        for (int t = l; t < SEQ; t += 64) {
            int lt = lb[t];
            int mt = mk[t];
            mcnt += mt;
            if (t == 0) {
                part += startt[lt] + em[lt];
            } else {
                float e  = em[t * NL + lt];
                float tr = trans[lt * NL + lb[t - 1]];   // gold uses T[cur][prev]
                if (mt) part += e + tr;
            }
        }
        #pragma unroll
        for (int o = 32; o; o >>= 1) {
            part += __shfl_xor(part, o);
            mcnt += __shfl_xor(mcnt, o);
        }
        if (l == 0) {
            int len = mcnt - 1;
            gold_out[b] = part + endt[lb[len]];
        }
    }
}

__global__ __launch_bounds__(64) void crf_reduce(
    const float* __restrict__ gold, const float* __restrict__ fwd,
    float* __restrict__ out)
{
    const int l = threadIdx.x;
    float s = 0.0f;
    for (int bIdx = l; bIdx < BATCH; bIdx += 64) s += fwd[bIdx] - gold[bIdx];
    #pragma unroll
    for (int o = 32; o; o >>= 1) s += __shfl_xor(s, o);
    if (l == 0) out[0] = s * (1.0f / (float)BATCH);
}

extern "C" void kernel_launch(void* const* d_in, const int* in_sizes, int n_in,
                              void* d_out, int out_size, void* d_ws, size_t ws_size,
                              hipStream_t stream) {
    const float* emissions = (const float*)d_in[0];
    const int*   labels    = (const int*)d_in[1];
    const int*   mask      = (const int*)d_in[2];
    const float* trans     = (const float*)d_in[3];
    const float* startt    = (const float*)d_in[4];
    const float* endt      = (const float*)d_in[5];
    float*       out       = (float*)d_out;
    float*       wsf       = (float*)d_ws;   // [0..512) gold, [512..1024) fwd

    crf_fused<<<BATCH, 128, 0, stream>>>(emissions, labels, mask, trans, startt, endt,
                                         wsf, wsf + BATCH);
    crf_reduce<<<1, 64, 0, stream>>>(wsf, wsf + BATCH, out);
}